// Round 3
// baseline (23641.530 us; speedup 1.0000x reference)
//
#include <hip/hip_runtime.h>
#include <cstdint>
#include <cstddef>

typedef short bf8v __attribute__((ext_vector_type(8)));   // 8 bf16 (4 VGPRs)
typedef float f4v  __attribute__((ext_vector_type(4)));   // 4 fp32 acc

#define NT 512
#define NB 64
#define NH 1024
#define NG 4096
#define BH (NB * NH)   // 65536

__device__ __forceinline__ unsigned short f2bf(float f) {
    union { float f; unsigned int i; } v; v.f = f;
    unsigned int u = v.i;
    u += 0x7FFFu + ((u >> 16) & 1u);   // RNE
    return (unsigned short)(u >> 16);
}
__device__ __forceinline__ float gclamp(float x) { return fminf(30.0f, fmaxf(-30.0f, x)); }
__device__ __forceinline__ float sigm(float x)  { x = gclamp(x); return 1.0f / (1.0f + __expf(-x)); }
__device__ __forceinline__ float tanhx(float x) { x = gclamp(x); return 2.0f / (1.0f + __expf(-2.0f * x)) - 1.0f; }

// ---------------------------------------------------------------------------
// fp32 -> bf16 weight conversion: 8 elements per thread
// ---------------------------------------------------------------------------
__global__ __launch_bounds__(256)
void wconv_kernel(const float* __restrict__ src, unsigned short* __restrict__ dst)
{
    const size_t i = ((size_t)blockIdx.x * 256 + threadIdx.x) * 8;
    const float4 f0 = *reinterpret_cast<const float4*>(src + i);
    const float4 f1 = *reinterpret_cast<const float4*>(src + i + 4);
    __align__(16) unsigned short t[8];
    t[0] = f2bf(f0.x); t[1] = f2bf(f0.y); t[2] = f2bf(f0.z); t[3] = f2bf(f0.w);
    t[4] = f2bf(f1.x); t[5] = f2bf(f1.y); t[6] = f2bf(f1.z); t[7] = f2bf(f1.w);
    *reinterpret_cast<uint4*>(dst + i) = *reinterpret_cast<const uint4*>(t);
}

// ---------------------------------------------------------------------------
// c_state = c0 (fp32 copy), hb0 = bf16(h0)
// ---------------------------------------------------------------------------
__global__ __launch_bounds__(256)
void init_kernel(const float* __restrict__ h0, const float* __restrict__ c0,
                 float* __restrict__ c_state, unsigned short* __restrict__ hb0)
{
    const int i = (blockIdx.x * 256 + threadIdx.x) * 4;
#pragma unroll
    for (int k = 0; k < 4; ++k) {
        c_state[i + k] = c0[i + k];
        hb0[i + k] = f2bf(h0[i + k]);
    }
}

// ---------------------------------------------------------------------------
// One LSTM timestep:
//   gates[64, 4H] = h_prev @ Whh^T + x_t @ Wih^T   (bf16 MFMA, K = 1024+1024)
// grid 64 blocks x 256 thr. Block b owns gate columns {g*1024 + b*16 .. +15}.
// Wave w = gate group w. h feedback bf16 via ws double-buffer; x converted
// fp32->bf16 at staging; weights preconverted bf16. State c fp32, out fp32.
// ---------------------------------------------------------------------------
__global__ __launch_bounds__(256)
void step_kernel(const float* __restrict__ x_t,
                 const unsigned short* __restrict__ h_prev,   // bf16 [64][1024]
                 const unsigned short* __restrict__ Whh_b,    // bf16 [4096][1024]
                 const unsigned short* __restrict__ Wih_b,    // bf16 [4096][1024]
                 const float* __restrict__ bih,
                 const float* __restrict__ bhh,
                 float* __restrict__ c_state,
                 unsigned short* __restrict__ h_next,         // bf16 [64][1024]
                 float* __restrict__ out_h,
                 float* __restrict__ out_c,
                 const int is_last)
{
    __shared__ __align__(16) unsigned short As[64][32];       // 4 KB
    __shared__ __align__(16) unsigned short Bs[4][16][32];    // 4 KB
    __shared__ float gbuf[4][64][16];                         // 16 KB

    const int j0   = blockIdx.x * 16;     // per-gate column offset
    const int tid  = threadIdx.x;
    const int wave = tid >> 6;
    const int lane = tid & 63;
    const int cl   = lane & 15;
    const int quad = lane >> 4;

    f4v acc[4];
#pragma unroll
    for (int i = 0; i < 4; ++i) acc[i] = (f4v){0.f, 0.f, 0.f, 0.f};

    const int arow = tid >> 2;            // 0..63
    const int ac8  = (tid & 3) * 8;       // elem offset 0,8,16,24
    const int brow = lane >> 2;           // 0..15
    const int bc8  = (lane & 3) * 8;

    for (int kt = 0; kt < 64; ++kt) {
        const int phase = kt >> 5;        // 0: h @ Whh, 1: x @ Wih
        const int k0 = (kt & 31) * 32;
        __syncthreads();
        if (phase == 0) {
            // A: bf16 h_prev, direct 16B copy
            *reinterpret_cast<uint4*>(&As[arow][ac8]) =
                *reinterpret_cast<const uint4*>(h_prev + (size_t)arow * NH + k0 + ac8);
        } else {
            // A: fp32 x_t, convert 8 floats -> 8 bf16
            const float* xp = x_t + (size_t)arow * NH + k0 + ac8;
            const float4 f0 = *reinterpret_cast<const float4*>(xp);
            const float4 f1 = *reinterpret_cast<const float4*>(xp + 4);
            __align__(16) unsigned short t[8];
            t[0] = f2bf(f0.x); t[1] = f2bf(f0.y); t[2] = f2bf(f0.z); t[3] = f2bf(f0.w);
            t[4] = f2bf(f1.x); t[5] = f2bf(f1.y); t[6] = f2bf(f1.z); t[7] = f2bf(f1.w);
            *reinterpret_cast<uint4*>(&As[arow][ac8]) = *reinterpret_cast<const uint4*>(t);
        }
        {   // B: wave w stages its 16 preconverted weight rows
            const unsigned short* W = phase ? Wih_b : Whh_b;
            *reinterpret_cast<uint4*>(&Bs[wave][brow][bc8]) =
                *reinterpret_cast<const uint4*>(W + (size_t)(wave * NH + j0 + brow) * NH + k0 + bc8);
        }
        __syncthreads();
        const bf8v b = *reinterpret_cast<const bf8v*>(&Bs[wave][cl][quad * 8]);
#pragma unroll
        for (int mi = 0; mi < 4; ++mi) {
            const bf8v a = *reinterpret_cast<const bf8v*>(&As[mi * 16 + cl][quad * 8]);
            acc[mi] = __builtin_amdgcn_mfma_f32_16x16x32_bf16(a, b, acc[mi], 0, 0, 0);
        }
    }

    // epilogue: gates -> LDS (C/D: row = quad*4+r (batch), col = cl (gate col))
#pragma unroll
    for (int mi = 0; mi < 4; ++mi)
#pragma unroll
        for (int r = 0; r < 4; ++r)
            gbuf[wave][mi * 16 + quad * 4 + r][cl] = acc[mi][r];
    __syncthreads();

    // pointwise LSTM update: 64 batch x 16 cols, 4 elements per thread
#pragma unroll
    for (int q = 0; q < 4; ++q) {
        const int e   = tid + q * 256;
        const int m   = e >> 4;           // batch row
        const int n   = e & 15;
        const int col = j0 + n;           // per-gate column
        const float gi = gbuf[0][m][n] + bih[col]          + bhh[col];
        const float gf = gbuf[1][m][n] + bih[NH + col]     + bhh[NH + col];
        const float gg = gbuf[2][m][n] + bih[2 * NH + col] + bhh[2 * NH + col];
        const float go = gbuf[3][m][n] + bih[3 * NH + col] + bhh[3 * NH + col];
        const float ig = sigm(gi);
        const float fg = sigm(gf);
        const float g2 = tanhx(gg);
        const float og = sigm(go);
        const float cprev = c_state[m * NH + col];
        const float cn = fg * cprev + ig * g2;
        const float hn = og * tanhx(cn);
        c_state[m * NH + col] = cn;
        h_next[m * NH + col] = f2bf(hn);
        out_h[(size_t)m * NH + col] = hn;
        if (is_last) out_c[(size_t)m * NH + col] = cn;
    }
}

extern "C" void kernel_launch(void* const* d_in, const int* in_sizes, int n_in,
                              void* d_out, int out_size, void* d_ws, size_t ws_size,
                              hipStream_t stream)
{
    (void)in_sizes; (void)n_in; (void)out_size; (void)ws_size;
    const float* X   = (const float*)d_in[0];
    const float* h0  = (const float*)d_in[1];
    const float* c0  = (const float*)d_in[2];
    const float* Wih = (const float*)d_in[3];
    const float* Whh = (const float*)d_in[4];
    const float* bih = (const float*)d_in[5];
    const float* bhh = (const float*)d_in[6];
    float* out = (float*)d_out;

    // ws layout (bytes): c_state fp32[BH] | hb0 bf16[BH] | hb1 bf16[BH]
    //                    | Whh_b bf16[4M] | Wih_b bf16[4M]   (~16.5 MB total)
    char* ws = (char*)d_ws;
    float*          c_state = (float*)ws;                       // 262144 B
    unsigned short* hb0     = (unsigned short*)(ws + 262144);   // 131072 B
    unsigned short* hb1     = (unsigned short*)(ws + 393216);   // 131072 B
    unsigned short* Whh_b   = (unsigned short*)(ws + 524288);   // 8388608 B
    unsigned short* Wih_b   = (unsigned short*)(ws + 8912896);  // 8388608 B

    wconv_kernel<<<(NG * NH) / (256 * 8), 256, 0, stream>>>(Whh, Whh_b);
    wconv_kernel<<<(NG * NH) / (256 * 8), 256, 0, stream>>>(Wih, Wih_b);
    init_kernel<<<BH / (256 * 4), 256, 0, stream>>>(h0, c0, c_state, hb0);

    for (int t = 0; t < NT; ++t) {
        const unsigned short* hp = (t & 1) ? hb1 : hb0;
        unsigned short*       hn = (t & 1) ? hb0 : hb1;
        step_kernel<<<64, 256, 0, stream>>>(
            X + (size_t)t * BH,
            hp, Whh_b, Wih_b, bih, bhh,
            c_state, hn,
            out + (size_t)t * BH,
            out + (size_t)NT * BH,
            (t == NT - 1) ? 1 : 0);
    }
}